// Round 1
// baseline (411.415 us; speedup 1.0000x reference)
//
#include <hip/hip_runtime.h>
#include <stdint.h>

typedef __attribute__((ext_vector_type(8))) short s8v;     // 8 x bf16 bits
typedef __attribute__((ext_vector_type(4))) float f32x4;

#define HEADS 16
#define DH    64
#define SEG   512
#define PM    16
#define NKV   528      // PM + SEG
#define KVP   576      // padded keys
#define DIM   1024
#define NQKV  3072
#define MTOT  16384    // 2*8192

__device__ __forceinline__ unsigned short f2bf(float f) {
  union { float f; unsigned u; } v; v.f = f;
  unsigned r = v.u + 0x7fffu + ((v.u >> 16) & 1u);
  return (unsigned short)(r >> 16);
}

__device__ __forceinline__ void mfma_bf16(f32x4& c, s8v a, s8v b) {
  asm("v_mfma_f32_16x16x32_bf16 %0, %1, %2, %0" : "+v"(c) : "v"(a), "v"(b));
}

__device__ __forceinline__ void gload_lds16(const unsigned short* g, unsigned short* l) {
  __builtin_amdgcn_global_load_lds(
      (const __attribute__((address_space(1))) unsigned int*)g,
      (__attribute__((address_space(3))) unsigned int*)l, 16, 0, 0);
}

// ---------------- prep kernels ----------------
__global__ void prep_rope(float* costab, float* sintab) {
  int idx = blockIdx.x * 256 + threadIdx.x;   // 8192*32
  int n = idx >> 5, p = idx & 31;
  double inv = pow(10000.0, -(double)p / 32.0);
  double ang = (double)n * inv;
  costab[idx] = (float)cos(ang);
  sintab[idx] = (float)sin(ang);
}

__global__ void transpose_w(const float* in, unsigned short* out, int K, int N) {
  // in [K][N] f32 -> out [N][K] bf16
  __shared__ float tile[32][33];
  int n0 = blockIdx.x * 32, k0 = blockIdx.y * 32;
  int tx = threadIdx.x, ty = threadIdx.y;   // (32,8)
  for (int i = ty; i < 32; i += 8) tile[i][tx] = in[(size_t)(k0 + i) * N + n0 + tx];
  __syncthreads();
  for (int i = ty; i < 32; i += 8) out[(size_t)(n0 + i) * K + k0 + tx] = f2bf(tile[tx][i]);
}

__global__ void prep_pm(const float* pm_k, const float* pm_v,
                        unsigned short* k_ws, unsigned short* v_ws) {
  int idx = blockIdx.x * 256 + threadIdx.x;   // 32*16*16*64
  int d = idx & 63, t = (idx >> 6) & 15, h = (idx >> 10) & 15, bw = idx >> 14;
  int sh = bw * 16 + h;
  k_ws[((size_t)sh * KVP + t) * 64 + d] = f2bf(pm_k[((h * 16 + t) << 6) + d]);
  v_ws[((size_t)sh * 64 + d) * KVP + t] = f2bf(pm_v[((h * 16 + t) << 6) + d]);
}

__global__ void clear_vpad(unsigned short* v_ws) {
  int idx = blockIdx.x * 256 + threadIdx.x;   // 512*64*48
  int t = idx % 48; int rest = idx / 48; int d = rest & 63; int sh = rest >> 6;
  v_ws[((size_t)sh * 64 + d) * KVP + NKV + t] = 0;
}

// ---------------- rmsnorm ----------------
__global__ __launch_bounds__(256) void rmsnorm_k(const float* x, const float* w,
                                                 unsigned short* xn) {
  int row = blockIdx.x, tid = threadIdx.x;
  float4 v = ((const float4*)(x + (size_t)row * DIM))[tid];
  float ss = v.x * v.x + v.y * v.y + v.z * v.z + v.w * v.w;
  #pragma unroll
  for (int o = 32; o > 0; o >>= 1) ss += __shfl_xor(ss, o);
  __shared__ float red[4];
  if ((tid & 63) == 0) red[tid >> 6] = ss;
  __syncthreads();
  ss = red[0] + red[1] + red[2] + red[3];
  float rs = rsqrtf(ss * (1.0f / 1024.0f) + 1e-6f);
  float4 wv = ((const float4*)w)[tid];
  ushort4 o;
  o.x = f2bf(v.x * rs * wv.x); o.y = f2bf(v.y * rs * wv.y);
  o.z = f2bf(v.z * rs * wv.z); o.w = f2bf(v.w * rs * wv.w);
  ((ushort4*)(xn + (size_t)row * DIM))[tid] = o;
}

// ---------------- GEMM 1: qkv = xn @ WqkvT, fused rope + scatter ----------------
__global__ __launch_bounds__(256) void gemm_qkv(const unsigned short* A, const unsigned short* Bt,
                                                const float* costab, const float* sintab,
                                                unsigned short* q_ws, unsigned short* k_ws,
                                                unsigned short* v_ws) {
  __shared__ unsigned short Als[4096];
  __shared__ unsigned short Bls[4096];
  int tid = threadIdx.x, lane = tid & 63, wid = tid >> 6;
  int n0 = blockIdx.x * 128, m0 = blockIdx.y * 128;
  f32x4 acc[4][4] = {};
  int c2 = tid + 256;
  const unsigned short* ga1 = A + (size_t)(m0 + (tid >> 2)) * DIM + (tid & 3) * 8;
  const unsigned short* ga2 = A + (size_t)(m0 + (c2 >> 2)) * DIM + (c2 & 3) * 8;
  const unsigned short* gb1 = Bt + (size_t)(n0 + (tid >> 2)) * DIM + (tid & 3) * 8;
  const unsigned short* gb2 = Bt + (size_t)(n0 + (c2 >> 2)) * DIM + (c2 & 3) * 8;
  unsigned short* lA1 = &Als[wid * 512];
  unsigned short* lA2 = &Als[2048 + wid * 512];
  unsigned short* lB1 = &Bls[wid * 512];
  unsigned short* lB2 = &Bls[2048 + wid * 512];
  int mb = (wid >> 1) * 64, nb = (wid & 1) * 64;
  int lr = lane & 15, lg = lane >> 4;

  for (int kt = 0; kt < DIM; kt += 32) {
    gload_lds16(ga1 + kt, lA1);
    gload_lds16(ga2 + kt, lA2);
    gload_lds16(gb1 + kt, lB1);
    gload_lds16(gb2 + kt, lB2);
    __syncthreads();
    s8v a[4], b[4];
    #pragma unroll
    for (int i = 0; i < 4; i++) a[i] = *(const s8v*)&Als[(mb + i * 16 + lr) * 32 + lg * 8];
    #pragma unroll
    for (int i = 0; i < 4; i++) b[i] = *(const s8v*)&Bls[(nb + i * 16 + lr) * 32 + lg * 8];
    #pragma unroll
    for (int i = 0; i < 4; i++)
      #pragma unroll
      for (int j = 0; j < 4; j++)
        mfma_bf16(acc[i][j], a[i], b[j]);
    __syncthreads();
  }

  // epilogue: rope on q/k, scatter into attention layouts
  #pragma unroll
  for (int i = 0; i < 4; i++) {
    #pragma unroll
    for (int j = 0; j < 4; j++) {
      int colbase = n0 + nb + j * 16;          // wave-uniform
      int type = colbase >> 10;                // 0=q 1=k 2=v
      int hh = (colbase & 1023) >> 6;
      int d = (colbase & 63) + lr;
      int rowb = m0 + mb + i * 16 + lg * 4;
      f32x4 v = acc[i][j];
      if (type < 2) {
        int p = d >> 1;
        float vr[4];
        #pragma unroll
        for (int r = 0; r < 4; r++) {
          float partner = __shfl_xor(v[r], 1);
          int npos = (rowb + r) & 8191;
          float cth = costab[npos * 32 + p];
          float sth = sintab[npos * 32 + p];
          vr[r] = (d & 1) ? (v[r] * cth + partner * sth)
                          : (v[r] * cth - partner * sth);
        }
        #pragma unroll
        for (int r = 0; r < 4; r++) v[r] = vr[r];
      }
      #pragma unroll
      for (int r = 0; r < 4; r++) {
        int m = rowb + r;
        int bw = m >> 9, pos = m & 511;
        int sh = bw * 16 + hh;
        unsigned short bits = f2bf(v[r]);
        if (type == 0)      q_ws[((size_t)sh * SEG + pos) * 64 + d] = bits;
        else if (type == 1) k_ws[((size_t)sh * KVP + PM + pos) * 64 + d] = bits;
        else                v_ws[((size_t)sh * 64 + d) * KVP + PM + pos] = bits;
      }
    }
  }
}

// ---------------- attention ----------------
__global__ __launch_bounds__(256) void attn_k(const unsigned short* q_ws,
                                              const unsigned short* k_ws,
                                              const unsigned short* v_ws,
                                              unsigned short* attn_out) {
  __shared__ unsigned short Kls[64 * 72];   // [key][d] padded
  __shared__ unsigned short Vls[64 * 72];   // [d][key] padded
  __shared__ unsigned short Pls[128 * 72];  // per-wave 32 rows
  int bid = blockIdx.x;
  int qt = bid & 3, h = (bid >> 2) & 15, s = bid >> 6;
  int sh = s * 16 + h;
  int tid = threadIdx.x, lane = tid & 63, wid = tid >> 6;
  int lr = lane & 15, lg = lane >> 4;
  int qrow0 = qt * 128 + wid * 32;

  s8v qf[2][2];
  #pragma unroll
  for (int mi = 0; mi < 2; mi++)
    #pragma unroll
    for (int kk = 0; kk < 2; kk++) {
      size_t row = (size_t)sh * SEG + qrow0 + mi * 16 + lr;
      qf[mi][kk] = *(const s8v*)&q_ws[row * 64 + kk * 32 + lg * 8];
    }

  f32x4 O[2][4] = {};
  float mrun[2][4], lrun[2][4];
  #pragma unroll
  for (int mi = 0; mi < 2; mi++)
    #pragma unroll
    for (int r = 0; r < 4; r++) { mrun[mi][r] = -1e30f; lrun[mi][r] = 0.0f; }

  const unsigned short* kbase = k_ws + (size_t)sh * KVP * 64;
  const unsigned short* vbase = v_ws + (size_t)sh * 64 * KVP;
  int nchunk = 2 * qt + 3;

  for (int cc = 0; cc < nchunk; ++cc) {
    int kc0 = cc * 64;
    {
      int i1 = tid * 8, i2 = (tid + 256) * 8;
      *(s8v*)&Kls[(i1 >> 6) * 72 + (i1 & 63)] = *(const s8v*)&kbase[kc0 * 64 + i1];
      *(s8v*)&Kls[(i2 >> 6) * 72 + (i2 & 63)] = *(const s8v*)&kbase[kc0 * 64 + i2];
      *(s8v*)&Vls[(i1 >> 6) * 72 + (i1 & 63)] =
          *(const s8v*)&vbase[(size_t)(i1 >> 6) * KVP + kc0 + (i1 & 63)];
      *(s8v*)&Vls[(i2 >> 6) * 72 + (i2 & 63)] =
          *(const s8v*)&vbase[(size_t)(i2 >> 6) * KVP + kc0 + (i2 & 63)];
    }
    __syncthreads();

    f32x4 S[2][4] = {};
    #pragma unroll
    for (int kk = 0; kk < 2; kk++)
      #pragma unroll
      for (int ni = 0; ni < 4; ni++) {
        s8v bf = *(const s8v*)&Kls[(ni * 16 + lr) * 72 + kk * 32 + lg * 8];
        #pragma unroll
        for (int mi = 0; mi < 2; mi++) mfma_bf16(S[mi][ni], qf[mi][kk], bf);
      }

    #pragma unroll
    for (int mi = 0; mi < 2; mi++) {
      #pragma unroll
      for (int r = 0; r < 4; r++) {
        int qpos = qrow0 + mi * 16 + lg * 4 + r;
        float mx = -1e30f;
        float sv[4];
        #pragma unroll
        for (int ni = 0; ni < 4; ni++) {
          int col = kc0 + ni * 16 + lr;
          float xv = S[mi][ni][r] * 0.125f;
          bool ok = (col < PM) || ((col - PM) <= qpos);
          xv = ok ? xv : -1e30f;
          sv[ni] = xv;
          mx = fmaxf(mx, xv);
        }
        #pragma unroll
        for (int o = 1; o < 16; o <<= 1) mx = fmaxf(mx, __shfl_xor(mx, o));
        float mnew = fmaxf(mrun[mi][r], mx);
        float scl = __expf(mrun[mi][r] - mnew);
        mrun[mi][r] = mnew;
        float rs = 0.0f;
        #pragma unroll
        for (int ni = 0; ni < 4; ni++) {
          float p = __expf(sv[ni] - mnew);
          S[mi][ni][r] = p;
          rs += p;
        }
        #pragma unroll
        for (int o = 1; o < 16; o <<= 1) rs += __shfl_xor(rs, o);
        lrun[mi][r] = lrun[mi][r] * scl + rs;
        #pragma unroll
        for (int oi = 0; oi < 4; oi++) O[mi][oi][r] *= scl;
      }
    }

    // P -> LDS (per-wave private region; same-wave DS ordering is in-order)
    #pragma unroll
    for (int mi = 0; mi < 2; mi++)
      #pragma unroll
      for (int ni = 0; ni < 4; ni++)
        #pragma unroll
        for (int r = 0; r < 4; r++)
          Pls[(wid * 32 + mi * 16 + lg * 4 + r) * 72 + ni * 16 + lr] = f2bf(S[mi][ni][r]);

    #pragma unroll
    for (int kk = 0; kk < 2; kk++) {
      s8v pa[2];
      #pragma unroll
      for (int mi = 0; mi < 2; mi++)
        pa[mi] = *(const s8v*)&Pls[(wid * 32 + mi * 16 + lr) * 72 + kk * 32 + lg * 8];
      #pragma unroll
      for (int oi = 0; oi < 4; oi++) {
        s8v vb = *(const s8v*)&Vls[(oi * 16 + lr) * 72 + kk * 32 + lg * 8];
        #pragma unroll
        for (int mi = 0; mi < 2; mi++) mfma_bf16(O[mi][oi], pa[mi], vb);
      }
    }
    __syncthreads();
  }

  int mbase = (s >> 4) * 8192 + (s & 15) * 512;
  #pragma unroll
  for (int mi = 0; mi < 2; mi++)
    #pragma unroll
    for (int r = 0; r < 4; r++) {
      float inv = 1.0f / lrun[mi][r];
      int qpos = qrow0 + mi * 16 + lg * 4 + r;
      size_t m = (size_t)mbase + qpos;
      #pragma unroll
      for (int oi = 0; oi < 4; oi++)
        attn_out[m * DIM + h * 64 + oi * 16 + lr] = f2bf(O[mi][oi][r] * inv);
    }
}

// ---------------- GEMM 2: out = attn @ WoutT + b ----------------
__global__ __launch_bounds__(256) void gemm_out(const unsigned short* A, const unsigned short* Bt,
                                                const float* bias, float* out) {
  __shared__ unsigned short Als[4096];
  __shared__ unsigned short Bls[4096];
  int tid = threadIdx.x, lane = tid & 63, wid = tid >> 6;
  int n0 = blockIdx.x * 128, m0 = blockIdx.y * 128;
  f32x4 acc[4][4] = {};
  int c2 = tid + 256;
  const unsigned short* ga1 = A + (size_t)(m0 + (tid >> 2)) * DIM + (tid & 3) * 8;
  const unsigned short* ga2 = A + (size_t)(m0 + (c2 >> 2)) * DIM + (c2 & 3) * 8;
  const unsigned short* gb1 = Bt + (size_t)(n0 + (tid >> 2)) * DIM + (tid & 3) * 8;
  const unsigned short* gb2 = Bt + (size_t)(n0 + (c2 >> 2)) * DIM + (c2 & 3) * 8;
  unsigned short* lA1 = &Als[wid * 512];
  unsigned short* lA2 = &Als[2048 + wid * 512];
  unsigned short* lB1 = &Bls[wid * 512];
  unsigned short* lB2 = &Bls[2048 + wid * 512];
  int mb = (wid >> 1) * 64, nb = (wid & 1) * 64;
  int lr = lane & 15, lg = lane >> 4;

  for (int kt = 0; kt < DIM; kt += 32) {
    gload_lds16(ga1 + kt, lA1);
    gload_lds16(ga2 + kt, lA2);
    gload_lds16(gb1 + kt, lB1);
    gload_lds16(gb2 + kt, lB2);
    __syncthreads();
    s8v a[4], b[4];
    #pragma unroll
    for (int i = 0; i < 4; i++) a[i] = *(const s8v*)&Als[(mb + i * 16 + lr) * 32 + lg * 8];
    #pragma unroll
    for (int i = 0; i < 4; i++) b[i] = *(const s8v*)&Bls[(nb + i * 16 + lr) * 32 + lg * 8];
    #pragma unroll
    for (int i = 0; i < 4; i++)
      #pragma unroll
      for (int j = 0; j < 4; j++)
        mfma_bf16(acc[i][j], a[i], b[j]);
    __syncthreads();
  }

  #pragma unroll
  for (int i = 0; i < 4; i++)
    #pragma unroll
    for (int j = 0; j < 4; j++) {
      int c = n0 + nb + j * 16 + lr;
      float bv = bias[c];
      #pragma unroll
      for (int r = 0; r < 4; r++) {
        int m = m0 + mb + i * 16 + lg * 4 + r;
        out[(size_t)m * DIM + c] = acc[i][j][r] + bv;
      }
    }
}

// ---------------- launch ----------------
extern "C" void kernel_launch(void* const* d_in, const int* in_sizes, int n_in,
                              void* d_out, int out_size, void* d_ws, size_t ws_size,
                              hipStream_t stream) {
  (void)in_sizes; (void)n_in; (void)out_size; (void)ws_size;
  const float* seq    = (const float*)d_in[0];
  const float* norm_w = (const float*)d_in[1];
  const float* w_qkv  = (const float*)d_in[2];
  const float* pm_k   = (const float*)d_in[3];
  const float* pm_v   = (const float*)d_in[4];
  const float* w_out  = (const float*)d_in[5];
  const float* b_out  = (const float*)d_in[6];
  float* out = (float*)d_out;

  char* ws = (char*)d_ws;
  unsigned short* xn    = (unsigned short*)(ws);              // 33,554,432 B
  unsigned short* wqkvT = (unsigned short*)(ws + 33554432);   //  6,291,456
  unsigned short* woutT = (unsigned short*)(ws + 39845888);   //  2,097,152
  float* costab         = (float*)(ws + 41943040);            //  1,048,576
  float* sintab         = (float*)(ws + 42991616);            //  1,048,576
  unsigned short* q_ws  = (unsigned short*)(ws + 44040192);   // 33,554,432
  unsigned short* k_ws  = (unsigned short*)(ws + 77594624);   // 37,748,736
  unsigned short* v_ws  = (unsigned short*)(ws + 115343360);  // 37,748,736
  unsigned short* attno = (unsigned short*)(ws + 153092096);  // 33,554,432 (end 186,646,528)

  prep_rope<<<1024, 256, 0, stream>>>(costab, sintab);
  transpose_w<<<dim3(96, 32), dim3(32, 8), 0, stream>>>(w_qkv, wqkvT, 1024, 3072);
  transpose_w<<<dim3(32, 32), dim3(32, 8), 0, stream>>>(w_out, woutT, 1024, 1024);
  prep_pm<<<2048, 256, 0, stream>>>(pm_k, pm_v, k_ws, v_ws);
  clear_vpad<<<6144, 256, 0, stream>>>(v_ws);
  rmsnorm_k<<<16384, 256, 0, stream>>>(seq, norm_w, xn);
  gemm_qkv<<<dim3(24, 128), 256, 0, stream>>>(xn, wqkvT, costab, sintab, q_ws, k_ws, v_ws);
  attn_k<<<2048, 256, 0, stream>>>(q_ws, k_ws, v_ws, attno);
  gemm_out<<<dim3(8, 128), 256, 0, stream>>>(attno, woutT, b_out, out);
}

// Round 2
// 372.542 us; speedup vs baseline: 1.1043x; 1.1043x over previous
//
#include <hip/hip_runtime.h>
#include <stdint.h>

typedef __attribute__((ext_vector_type(8))) short s8v;     // 8 x bf16 bits
typedef __attribute__((ext_vector_type(4))) float f32x4;

#define HEADS 16
#define DH    64
#define SEG   512
#define PM    16
#define NKV   528      // PM + SEG
#define KVP   576      // padded keys
#define DIM   1024
#define NQKV  3072
#define MTOT  16384    // 2*8192

__device__ __forceinline__ unsigned short f2bf(float f) {
  union { float f; unsigned u; } v; v.f = f;
  unsigned r = v.u + 0x7fffu + ((v.u >> 16) & 1u);
  return (unsigned short)(r >> 16);
}

__device__ __forceinline__ void mfma_bf16(f32x4& c, s8v a, s8v b) {
  asm("v_mfma_f32_16x16x32_bf16 %0, %1, %2, %0" : "+v"(c) : "v"(a), "v"(b));
}

__device__ __forceinline__ void gload_lds16(const unsigned short* g, unsigned short* l) {
  __builtin_amdgcn_global_load_lds(
      (const __attribute__((address_space(1))) unsigned int*)g,
      (__attribute__((address_space(3))) unsigned int*)l, 16, 0, 0);
}

// ---------------- prep kernels ----------------
__global__ void prep_rope(float* costab, float* sintab) {
  int idx = blockIdx.x * 256 + threadIdx.x;   // 8192*32
  int n = idx >> 5, p = idx & 31;
  double inv = pow(10000.0, -(double)p / 32.0);
  double ang = (double)n * inv;
  costab[idx] = (float)cos(ang);
  sintab[idx] = (float)sin(ang);
}

__global__ void transpose_w(const float* in, unsigned short* out, int K, int N) {
  // in [K][N] f32 -> out [N][K] bf16
  __shared__ float tile[32][33];
  int n0 = blockIdx.x * 32, k0 = blockIdx.y * 32;
  int tx = threadIdx.x, ty = threadIdx.y;   // (32,8)
  for (int i = ty; i < 32; i += 8) tile[i][tx] = in[(size_t)(k0 + i) * N + n0 + tx];
  __syncthreads();
  for (int i = ty; i < 32; i += 8) out[(size_t)(n0 + i) * K + k0 + tx] = f2bf(tile[tx][i]);
}

__global__ void prep_pm(const float* pm_k, const float* pm_v,
                        unsigned short* k_ws, unsigned short* v_ws) {
  int idx = blockIdx.x * 256 + threadIdx.x;   // 32*16*16*64
  int d = idx & 63, t = (idx >> 6) & 15, h = (idx >> 10) & 15, bw = idx >> 14;
  int sh = bw * 16 + h;
  k_ws[((size_t)sh * KVP + t) * 64 + d] = f2bf(pm_k[((h * 16 + t) << 6) + d]);
  v_ws[((size_t)sh * 64 + d) * KVP + t] = f2bf(pm_v[((h * 16 + t) << 6) + d]);
}

__global__ void clear_vpad(unsigned short* v_ws) {
  int idx = blockIdx.x * 256 + threadIdx.x;   // 512*64*48
  int t = idx % 48; int rest = idx / 48; int d = rest & 63; int sh = rest >> 6;
  v_ws[((size_t)sh * 64 + d) * KVP + NKV + t] = 0;
}

// ---------------- rmsnorm ----------------
__global__ __launch_bounds__(256) void rmsnorm_k(const float* x, const float* w,
                                                 unsigned short* xn) {
  int row = blockIdx.x, tid = threadIdx.x;
  float4 v = ((const float4*)(x + (size_t)row * DIM))[tid];
  float ss = v.x * v.x + v.y * v.y + v.z * v.z + v.w * v.w;
  #pragma unroll
  for (int o = 32; o > 0; o >>= 1) ss += __shfl_xor(ss, o);
  __shared__ float red[4];
  if ((tid & 63) == 0) red[tid >> 6] = ss;
  __syncthreads();
  ss = red[0] + red[1] + red[2] + red[3];
  float rs = rsqrtf(ss * (1.0f / 1024.0f) + 1e-6f);
  float4 wv = ((const float4*)w)[tid];
  ushort4 o;
  o.x = f2bf(v.x * rs * wv.x); o.y = f2bf(v.y * rs * wv.y);
  o.z = f2bf(v.z * rs * wv.z); o.w = f2bf(v.w * rs * wv.w);
  ((ushort4*)(xn + (size_t)row * DIM))[tid] = o;
}

// ---------------- GEMM 1: qkv = xn @ WqkvT, fused rope + scatter ----------------
__global__ __launch_bounds__(256) void gemm_qkv(const unsigned short* A, const unsigned short* Bt,
                                                const float* costab, const float* sintab,
                                                unsigned short* q_ws, unsigned short* k_ws,
                                                unsigned short* v_ws) {
  __shared__ unsigned short Als[4096];
  __shared__ unsigned short Bls[4096];
  int tid = threadIdx.x, lane = tid & 63, wid = tid >> 6;
  int n0 = blockIdx.x * 128, m0 = blockIdx.y * 128;
  f32x4 acc[4][4] = {};
  int c2 = tid + 256;
  const unsigned short* ga1 = A + (size_t)(m0 + (tid >> 2)) * DIM + (tid & 3) * 8;
  const unsigned short* ga2 = A + (size_t)(m0 + (c2 >> 2)) * DIM + (c2 & 3) * 8;
  const unsigned short* gb1 = Bt + (size_t)(n0 + (tid >> 2)) * DIM + (tid & 3) * 8;
  const unsigned short* gb2 = Bt + (size_t)(n0 + (c2 >> 2)) * DIM + (c2 & 3) * 8;
  unsigned short* lA1 = &Als[wid * 512];
  unsigned short* lA2 = &Als[2048 + wid * 512];
  unsigned short* lB1 = &Bls[wid * 512];
  unsigned short* lB2 = &Bls[2048 + wid * 512];
  int mb = (wid >> 1) * 64, nb = (wid & 1) * 64;
  int lr = lane & 15, lg = lane >> 4;

  for (int kt = 0; kt < DIM; kt += 32) {
    gload_lds16(ga1 + kt, lA1);
    gload_lds16(ga2 + kt, lA2);
    gload_lds16(gb1 + kt, lB1);
    gload_lds16(gb2 + kt, lB2);
    __syncthreads();
    s8v a[4], b[4];
    #pragma unroll
    for (int i = 0; i < 4; i++) a[i] = *(const s8v*)&Als[(mb + i * 16 + lr) * 32 + lg * 8];
    #pragma unroll
    for (int i = 0; i < 4; i++) b[i] = *(const s8v*)&Bls[(nb + i * 16 + lr) * 32 + lg * 8];
    #pragma unroll
    for (int i = 0; i < 4; i++)
      #pragma unroll
      for (int j = 0; j < 4; j++)
        mfma_bf16(acc[i][j], a[i], b[j]);
    __syncthreads();
  }

  // epilogue: rope on q/k, scatter into attention layouts.
  // type is block-uniform (region boundaries at 1024 are multiples of 128).
  #pragma unroll
  for (int i = 0; i < 4; i++) {
    #pragma unroll
    for (int j = 0; j < 4; j++) {
      int colbase = n0 + nb + j * 16;          // wave-uniform
      int type = colbase >> 10;                // 0=q 1=k 2=v
      int hh = (colbase & 1023) >> 6;
      int d0 = colbase & 63;
      int d = d0 + lr;
      int rowt = m0 + mb + i * 16;             // tile row base (no lg)
      int rowb = rowt + lg * 4;
      f32x4 v = acc[i][j];
      if (type < 2) {
        int p = d >> 1;
        float vr[4];
        #pragma unroll
        for (int r = 0; r < 4; r++) {
          float partner = __shfl_xor(v[r], 1);
          int npos = (rowb + r) & 8191;
          float cth = costab[npos * 32 + p];
          float sth = sintab[npos * 32 + p];
          vr[r] = (d & 1) ? (v[r] * cth + partner * sth)
                          : (v[r] * cth - partner * sth);
        }
        #pragma unroll
        for (int r = 0; r < 4; r++) {
          int m = rowb + r;
          int bw = m >> 9, pos = m & 511;
          int sh = bw * 16 + hh;
          unsigned short bits = f2bf(vr[r]);
          if (type == 0) q_ws[((size_t)sh * SEG + pos) * 64 + d] = bits;
          else           k_ws[((size_t)sh * KVP + PM + pos) * 64 + d] = bits;
        }
      } else {
        // V: transpose 16x16 tile through wave-private LDS so global stores
        // are contiguous along pos (16 lanes x 2B = 32B segments instead of
        // 64 scattered 2B stores). Als is free after the last __syncthreads.
        unsigned short* T = &Als[wid * 1024];
        #pragma unroll
        for (int r = 0; r < 4; r++)
          T[lr * 17 + lg * 4 + r] = f2bf(v[r]);        // T[d_local][pos_local]
        int sh = (rowt >> 9) * 16 + hh;
        int pos0 = rowt & 511;
        #pragma unroll
        for (int r2 = 0; r2 < 4; r2++) {
          int dloc = lg * 4 + r2;
          unsigned short bits = T[dloc * 17 + lr];
          v_ws[((size_t)sh * 64 + d0 + dloc) * KVP + PM + pos0 + lr] = bits;
        }
      }
    }
  }
}

// ---------------- attention ----------------
__global__ __launch_bounds__(256) void attn_k(const unsigned short* q_ws,
                                              const unsigned short* k_ws,
                                              const unsigned short* v_ws,
                                              unsigned short* attn_out) {
  __shared__ unsigned short Kls[64 * 72];   // [key][d] padded
  __shared__ unsigned short Vls[64 * 72];   // [d][key] padded
  __shared__ unsigned short Pls[128 * 72];  // per-wave 32 rows
  int bid = blockIdx.x;
  int qt = bid & 3, h = (bid >> 2) & 15, s = bid >> 6;
  int sh = s * 16 + h;
  int tid = threadIdx.x, lane = tid & 63, wid = tid >> 6;
  int lr = lane & 15, lg = lane >> 4;
  int qrow0 = qt * 128 + wid * 32;

  s8v qf[2][2];
  #pragma unroll
  for (int mi = 0; mi < 2; mi++)
    #pragma unroll
    for (int kk = 0; kk < 2; kk++) {
      size_t row = (size_t)sh * SEG + qrow0 + mi * 16 + lr;
      qf[mi][kk] = *(const s8v*)&q_ws[row * 64 + kk * 32 + lg * 8];
    }

  f32x4 O[2][4] = {};
  float mrun[2][4], lrun[2][4];
  #pragma unroll
  for (int mi = 0; mi < 2; mi++)
    #pragma unroll
    for (int r = 0; r < 4; r++) { mrun[mi][r] = -1e30f; lrun[mi][r] = 0.0f; }

  const unsigned short* kbase = k_ws + (size_t)sh * KVP * 64;
  const unsigned short* vbase = v_ws + (size_t)sh * 64 * KVP;
  int nchunk = 2 * qt + 3;

  for (int cc = 0; cc < nchunk; ++cc) {
    int kc0 = cc * 64;
    {
      int i1 = tid * 8, i2 = (tid + 256) * 8;
      *(s8v*)&Kls[(i1 >> 6) * 72 + (i1 & 63)] = *(const s8v*)&kbase[kc0 * 64 + i1];
      *(s8v*)&Kls[(i2 >> 6) * 72 + (i2 & 63)] = *(const s8v*)&kbase[kc0 * 64 + i2];
      *(s8v*)&Vls[(i1 >> 6) * 72 + (i1 & 63)] =
          *(const s8v*)&vbase[(size_t)(i1 >> 6) * KVP + kc0 + (i1 & 63)];
      *(s8v*)&Vls[(i2 >> 6) * 72 + (i2 & 63)] =
          *(const s8v*)&vbase[(size_t)(i2 >> 6) * KVP + kc0 + (i2 & 63)];
    }
    __syncthreads();

    f32x4 S[2][4] = {};
    #pragma unroll
    for (int kk = 0; kk < 2; kk++)
      #pragma unroll
      for (int ni = 0; ni < 4; ni++) {
        s8v bf = *(const s8v*)&Kls[(ni * 16 + lr) * 72 + kk * 32 + lg * 8];
        #pragma unroll
        for (int mi = 0; mi < 2; mi++) mfma_bf16(S[mi][ni], qf[mi][kk], bf);
      }

    #pragma unroll
    for (int mi = 0; mi < 2; mi++) {
      #pragma unroll
      for (int r = 0; r < 4; r++) {
        int qpos = qrow0 + mi * 16 + lg * 4 + r;
        float mx = -1e30f;
        float sv[4];
        #pragma unroll
        for (int ni = 0; ni < 4; ni++) {
          int col = kc0 + ni * 16 + lr;
          float xv = S[mi][ni][r] * 0.125f;
          bool ok = (col < PM) || ((col - PM) <= qpos);
          xv = ok ? xv : -1e30f;
          sv[ni] = xv;
          mx = fmaxf(mx, xv);
        }
        #pragma unroll
        for (int o = 1; o < 16; o <<= 1) mx = fmaxf(mx, __shfl_xor(mx, o));
        float mnew = fmaxf(mrun[mi][r], mx);
        float scl = __expf(mrun[mi][r] - mnew);
        mrun[mi][r] = mnew;
        float rs = 0.0f;
        #pragma unroll
        for (int ni = 0; ni < 4; ni++) {
          float p = __expf(sv[ni] - mnew);
          S[mi][ni][r] = p;
          rs += p;
        }
        #pragma unroll
        for (int o = 1; o < 16; o <<= 1) rs += __shfl_xor(rs, o);
        lrun[mi][r] = lrun[mi][r] * scl + rs;
        #pragma unroll
        for (int oi = 0; oi < 4; oi++) O[mi][oi][r] *= scl;
      }
    }

    // P -> LDS (per-wave private region; same-wave DS ordering is in-order)
    #pragma unroll
    for (int mi = 0; mi < 2; mi++)
      #pragma unroll
      for (int ni = 0; ni < 4; ni++)
        #pragma unroll
        for (int r = 0; r < 4; r++)
          Pls[(wid * 32 + mi * 16 + lg * 4 + r) * 72 + ni * 16 + lr] = f2bf(S[mi][ni][r]);

    #pragma unroll
    for (int kk = 0; kk < 2; kk++) {
      s8v pa[2];
      #pragma unroll
      for (int mi = 0; mi < 2; mi++)
        pa[mi] = *(const s8v*)&Pls[(wid * 32 + mi * 16 + lr) * 72 + kk * 32 + lg * 8];
      #pragma unroll
      for (int oi = 0; oi < 4; oi++) {
        s8v vb = *(const s8v*)&Vls[(oi * 16 + lr) * 72 + kk * 32 + lg * 8];
        #pragma unroll
        for (int mi = 0; mi < 2; mi++) mfma_bf16(O[mi][oi], pa[mi], vb);
      }
    }
    __syncthreads();
  }

  int mbase = (s >> 4) * 8192 + (s & 15) * 512;
  #pragma unroll
  for (int mi = 0; mi < 2; mi++)
    #pragma unroll
    for (int r = 0; r < 4; r++) {
      float inv = 1.0f / lrun[mi][r];
      int qpos = qrow0 + mi * 16 + lg * 4 + r;
      size_t m = (size_t)mbase + qpos;
      #pragma unroll
      for (int oi = 0; oi < 4; oi++)
        attn_out[m * DIM + h * 64 + oi * 16 + lr] = f2bf(O[mi][oi][r] * inv);
    }
}

// ---------------- GEMM 2: out = attn @ WoutT + b ----------------
__global__ __launch_bounds__(256) void gemm_out(const unsigned short* A, const unsigned short* Bt,
                                                const float* bias, float* out) {
  __shared__ unsigned short Als[4096];
  __shared__ unsigned short Bls[4096];
  int tid = threadIdx.x, lane = tid & 63, wid = tid >> 6;
  int n0 = blockIdx.x * 128, m0 = blockIdx.y * 128;
  f32x4 acc[4][4] = {};
  int c2 = tid + 256;
  const unsigned short* ga1 = A + (size_t)(m0 + (tid >> 2)) * DIM + (tid & 3) * 8;
  const unsigned short* ga2 = A + (size_t)(m0 + (c2 >> 2)) * DIM + (c2 & 3) * 8;
  const unsigned short* gb1 = Bt + (size_t)(n0 + (tid >> 2)) * DIM + (tid & 3) * 8;
  const unsigned short* gb2 = Bt + (size_t)(n0 + (c2 >> 2)) * DIM + (c2 & 3) * 8;
  unsigned short* lA1 = &Als[wid * 512];
  unsigned short* lA2 = &Als[2048 + wid * 512];
  unsigned short* lB1 = &Bls[wid * 512];
  unsigned short* lB2 = &Bls[2048 + wid * 512];
  int mb = (wid >> 1) * 64, nb = (wid & 1) * 64;
  int lr = lane & 15, lg = lane >> 4;

  for (int kt = 0; kt < DIM; kt += 32) {
    gload_lds16(ga1 + kt, lA1);
    gload_lds16(ga2 + kt, lA2);
    gload_lds16(gb1 + kt, lB1);
    gload_lds16(gb2 + kt, lB2);
    __syncthreads();
    s8v a[4], b[4];
    #pragma unroll
    for (int i = 0; i < 4; i++) a[i] = *(const s8v*)&Als[(mb + i * 16 + lr) * 32 + lg * 8];
    #pragma unroll
    for (int i = 0; i < 4; i++) b[i] = *(const s8v*)&Bls[(nb + i * 16 + lr) * 32 + lg * 8];
    #pragma unroll
    for (int i = 0; i < 4; i++)
      #pragma unroll
      for (int j = 0; j < 4; j++)
        mfma_bf16(acc[i][j], a[i], b[j]);
    __syncthreads();
  }

  #pragma unroll
  for (int i = 0; i < 4; i++)
    #pragma unroll
    for (int j = 0; j < 4; j++) {
      int c = n0 + nb + j * 16 + lr;
      float bv = bias[c];
      #pragma unroll
      for (int r = 0; r < 4; r++) {
        int m = m0 + mb + i * 16 + lg * 4 + r;
        out[(size_t)m * DIM + c] = acc[i][j][r] + bv;
      }
    }
}

// ---------------- launch ----------------
extern "C" void kernel_launch(void* const* d_in, const int* in_sizes, int n_in,
                              void* d_out, int out_size, void* d_ws, size_t ws_size,
                              hipStream_t stream) {
  (void)in_sizes; (void)n_in; (void)out_size; (void)ws_size;
  const float* seq    = (const float*)d_in[0];
  const float* norm_w = (const float*)d_in[1];
  const float* w_qkv  = (const float*)d_in[2];
  const float* pm_k   = (const float*)d_in[3];
  const float* pm_v   = (const float*)d_in[4];
  const float* w_out  = (const float*)d_in[5];
  const float* b_out  = (const float*)d_in[6];
  float* out = (float*)d_out;

  char* ws = (char*)d_ws;
  unsigned short* xn    = (unsigned short*)(ws);              // 33,554,432 B
  unsigned short* wqkvT = (unsigned short*)(ws + 33554432);   //  6,291,456
  unsigned short* woutT = (unsigned short*)(ws + 39845888);   //  2,097,152
  float* costab         = (float*)(ws + 41943040);            //  1,048,576
  float* sintab         = (float*)(ws + 42991616);            //  1,048,576
  unsigned short* q_ws  = (unsigned short*)(ws + 44040192);   // 33,554,432
  unsigned short* k_ws  = (unsigned short*)(ws + 77594624);   // 37,748,736
  unsigned short* v_ws  = (unsigned short*)(ws + 115343360);  // 37,748,736
  unsigned short* attno = (unsigned short*)(ws + 153092096);  // 33,554,432 (end 186,646,528)

  prep_rope<<<1024, 256, 0, stream>>>(costab, sintab);
  transpose_w<<<dim3(96, 32), dim3(32, 8), 0, stream>>>(w_qkv, wqkvT, 1024, 3072);
  transpose_w<<<dim3(32, 32), dim3(32, 8), 0, stream>>>(w_out, woutT, 1024, 1024);
  prep_pm<<<2048, 256, 0, stream>>>(pm_k, pm_v, k_ws, v_ws);
  clear_vpad<<<6144, 256, 0, stream>>>(v_ws);
  rmsnorm_k<<<16384, 256, 0, stream>>>(seq, norm_w, xn);
  gemm_qkv<<<dim3(24, 128), 256, 0, stream>>>(xn, wqkvT, costab, sintab, q_ws, k_ws, v_ws);
  attn_k<<<2048, 256, 0, stream>>>(q_ws, k_ws, v_ws, attno);
  gemm_out<<<dim3(8, 128), 256, 0, stream>>>(attno, woutT, b_out, out);
}